// Round 5
// baseline (713.529 us; speedup 1.0000x reference)
//
#include <hip/hip_runtime.h>

#define D 128
#define PSTRIDE 132                 // per-segment accumulator: 128 cols + s @128 (pad to 132)

// ---------------------------------------------------------------------------
// Kernel 0: block 0 computes the 7 column means; remaining blocks zero the
// per-segment partial accumulators (d_ws is poisoned 0xAA before every call).
// ---------------------------------------------------------------------------
__global__ __launch_bounds__(256) void prep_kernel(
        const float* __restrict__ de, const float* __restrict__ den, int M,
        float* __restrict__ means, float* __restrict__ partials, int nPartF4) {
    if (blockIdx.x == 0) {
        __shared__ float sm[256][8];
        float a[7];
#pragma unroll
        for (int j = 0; j < 7; ++j) a[j] = 0.f;
        for (int r = threadIdx.x; r < M; r += 256) {
#pragma unroll
            for (int j = 0; j < 6; ++j) a[j] += de[r * 6 + j];
            a[6] += den[r];
        }
#pragma unroll
        for (int j = 0; j < 7; ++j) sm[threadIdx.x][j] = a[j];
        __syncthreads();
        for (int s = 128; s > 0; s >>= 1) {
            if (threadIdx.x < (unsigned)s) {
#pragma unroll
                for (int j = 0; j < 7; ++j) sm[threadIdx.x][j] += sm[threadIdx.x + s][j];
            }
            __syncthreads();
        }
        if (threadIdx.x < 7) means[threadIdx.x] = sm[0][threadIdx.x] / (float)M;
    } else {
        const int i = (blockIdx.x - 1) * 256 + threadIdx.x;
        if (i < nPartF4) ((float4*)partials)[i] = make_float4(0.f, 0.f, 0.f, 0.f);
    }
}

// ---------------------------------------------------------------------------
// Kernel 1: persistent contiguous-stream pool. Each of the 8192 waves owns a
// contiguous rowsPerWave slice of x; quarter-wave q owns row i+q, lane l16
// holds 8 cols (two float4). Explicit register prefetch of iteration i+4's
// loads before processing iteration i. Shift-free softmax partials (s, sum
// e*x) are additive, so a wave accumulates for its CURRENT segment (seg is
// sorted -> monotone) and atomicAdds to partials[seg] at boundaries only.
// No barriers, no cross-wave traffic, identical work per wave.
// ---------------------------------------------------------------------------
__global__ __launch_bounds__(256) void stream_kernel(
        const float* __restrict__ x, const int* __restrict__ mask,
        const int* __restrict__ seg, int N, int rowsPerWave,
        const float* __restrict__ gate_w, const float* __restrict__ gate_b,
        float* __restrict__ partials) {
    const int tid  = threadIdx.x;
    const int wv   = tid >> 6;
    const int lane = tid & 63;
    const int q    = lane >> 4;
    const int l16  = lane & 15;

    const int gwave = blockIdx.x * 4 + wv;
    const int i0 = gwave * rowsPerWave;
    const int i1 = min(i0 + rowsPerWave, N);
    if (i0 >= i1) return;                       // wave-uniform exit, no barriers used
    const int last = i1 - 1;

    const float4 gwA = ((const float4*)gate_w)[l16];
    const float4 gwB = ((const float4*)gate_w)[16 + l16];
    const float  gb  = gate_b[0];

    int    cur  = seg[i0];                      // wave-uniform (broadcast load)
    float  s    = 0.f;
    float4 accA = {0.f, 0.f, 0.f, 0.f};
    float4 accB = {0.f, 0.f, 0.f, 0.f};

    // prefetch iteration 0
    int r0 = min(i0 + q, last);
    const float* xr0 = x + (size_t)r0 * D;
    float4 xa = ((const float4*)xr0)[l16];
    float4 xb = ((const float4*)xr0)[16 + l16];
    int    mk = mask[r0];
    int    sg = seg[r0];

    for (int i = i0; i < i1; i += 4) {
        // ---- prefetch iteration i+4 (clamped; tail re-reads last row, L1-hot)
        const int rn = min(i + 4 + q, last);
        const float* xrn = x + (size_t)rn * D;
        const float4 na  = ((const float4*)xrn)[l16];
        const float4 nb  = ((const float4*)xrn)[16 + l16];
        const int    nmk = mask[rn];
        const int    nsg = seg[rn];

        // ---- process iteration i
        float p = xa.x * gwA.x + xa.y * gwA.y + xa.z * gwA.z + xa.w * gwA.w
                + xb.x * gwB.x + xb.y * gwB.y + xb.z * gwB.z + xb.w * gwB.w;
#pragma unroll
        for (int o = 8; o > 0; o >>= 1) p += __shfl_xor(p, o);    // 16-lane reduce
        const bool rowok = (i + q < i1) && (mk != 0);

        while (true) {
            const float e = (rowok && sg == cur) ? __expf(p + gb) : 0.f;
            s      += e;
            accA.x += e * xa.x; accA.y += e * xa.y; accA.z += e * xa.z; accA.w += e * xa.w;
            accB.x += e * xb.x; accB.y += e * xb.y; accB.z += e * xb.z; accB.w += e * xb.w;
            const int sgmax = __shfl(sg, 63);   // lane63 = last (clamped) row; seg monotone
            if (sgmax == cur) break;
            // ---- flush `cur` (rare: ~1 per 61 iterations)
            {
#define RED4(v) v += __shfl_xor(v, 16); v += __shfl_xor(v, 32);
                RED4(accA.x) RED4(accA.y) RED4(accA.z) RED4(accA.w)
                RED4(accB.x) RED4(accB.y) RED4(accB.z) RED4(accB.w)
                RED4(s)
#undef RED4
                float* pb = partials + (size_t)cur * PSTRIDE;
                if (lane < 16) {
                    atomicAdd(pb + l16 * 4 + 0, accA.x);
                    atomicAdd(pb + l16 * 4 + 1, accA.y);
                    atomicAdd(pb + l16 * 4 + 2, accA.z);
                    atomicAdd(pb + l16 * 4 + 3, accA.w);
                    atomicAdd(pb + 64 + l16 * 4 + 0, accB.x);
                    atomicAdd(pb + 64 + l16 * 4 + 1, accB.y);
                    atomicAdd(pb + 64 + l16 * 4 + 2, accB.z);
                    atomicAdd(pb + 64 + l16 * 4 + 3, accB.w);
                }
                if (lane == 0) atomicAdd(pb + 128, s);
                s = 0.f;
                accA = make_float4(0.f, 0.f, 0.f, 0.f);
                accB = make_float4(0.f, 0.f, 0.f, 0.f);
            }
            // next segment present in this batch: min sg > cur (wave-uniform)
            int nx = (sg > cur) ? sg : 0x7fffffff;
            nx = min(nx, __shfl_xor(nx, 16));
            nx = min(nx, __shfl_xor(nx, 32));
            cur = nx;
        }

        xa = na; xb = nb; mk = nmk; sg = nsg;
    }

    // final flush
    {
#define RED4(v) v += __shfl_xor(v, 16); v += __shfl_xor(v, 32);
        RED4(accA.x) RED4(accA.y) RED4(accA.z) RED4(accA.w)
        RED4(accB.x) RED4(accB.y) RED4(accB.z) RED4(accB.w)
        RED4(s)
#undef RED4
        float* pb = partials + (size_t)cur * PSTRIDE;
        if (lane < 16) {
            atomicAdd(pb + l16 * 4 + 0, accA.x);
            atomicAdd(pb + l16 * 4 + 1, accA.y);
            atomicAdd(pb + l16 * 4 + 2, accA.z);
            atomicAdd(pb + l16 * 4 + 3, accA.w);
            atomicAdd(pb + 64 + l16 * 4 + 0, accB.x);
            atomicAdd(pb + 64 + l16 * 4 + 1, accB.y);
            atomicAdd(pb + 64 + l16 * 4 + 2, accB.z);
            atomicAdd(pb + 64 + l16 * 4 + 3, accB.w);
        }
        if (lane == 0) atomicAdd(pb + 128, s);
    }
}

// ---------------------------------------------------------------------------
// Kernel 2: normalize accumulated partials, fused MLPs, scaled outputs.
// ---------------------------------------------------------------------------
__global__ __launch_bounds__(256) void combine_mlp_kernel(
        const float* __restrict__ partials,
        const float* __restrict__ w1, const float* __restrict__ b1,
        const float* __restrict__ w2, const float* __restrict__ b2,
        const float* __restrict__ w1n, const float* __restrict__ b1n,
        const float* __restrict__ w2n, const float* __restrict__ b2n,
        const float* __restrict__ means,
        float* __restrict__ out_vec, float* __restrict__ out_norm) {
    const int b   = blockIdx.x;
    const int tid = threadIdx.x;
    const float* pb = partials + (size_t)b * PSTRIDE;

    __shared__ float xs[D];
    if (tid < D) {
        const float S = fmaxf(pb[128], 1e-12f);   // empty/all-masked -> xs=0 (matches ref)
        xs[tid] = pb[tid] / S;
    }
    __syncthreads();

    __shared__ float hid[D], hidn[D];
    if (tid < D) {
        float a1 = b1[tid];
#pragma unroll 8
        for (int i = 0; i < D; ++i) a1 += xs[i] * w1[i * D + tid];
        hid[tid] = fmaxf(a1, 0.f);
    } else {
        const int hh = tid - D;
        float a1n = b1n[hh];
#pragma unroll 8
        for (int i = 0; i < D; ++i) a1n += xs[i] * w1n[i * D + hh];
        hidn[hh] = fmaxf(a1n, 0.f);
    }
    __syncthreads();

    if (tid < 112) {
        const int g = tid >> 4, l = tid & 15;
        float o = 0.f;
        if (g < 6) {
#pragma unroll
            for (int k = 0; k < 8; ++k) { const int i = l * 8 + k; o += hid[i] * w2[i * 6 + g]; }
        } else {
#pragma unroll
            for (int k = 0; k < 8; ++k) { const int i = l * 8 + k; o += hidn[i] * w2n[i]; }
        }
#pragma unroll
        for (int of = 8; of > 0; of >>= 1) o += __shfl_xor(o, of);
        if (l == 0) {
            if (g < 6) out_vec[b * 6 + g] = (o + b2[g]) * means[g];
            else       out_norm[b]        = (o + b2n[0]) * means[6];
        }
    }
}

extern "C" void kernel_launch(void* const* d_in, const int* in_sizes, int n_in,
                              void* d_out, int out_size, void* d_ws, size_t ws_size,
                              hipStream_t stream) {
    const float* x      = (const float*)d_in[0];
    const int*   mask   = (const int*)  d_in[1];
    const int*   seg    = (const int*)  d_in[2];
    const float* de     = (const float*)d_in[3];
    const float* den    = (const float*)d_in[4];
    const float* gate_w = (const float*)d_in[5];
    const float* gate_b = (const float*)d_in[6];
    const float* w1     = (const float*)d_in[7];
    const float* b1     = (const float*)d_in[8];
    const float* w2     = (const float*)d_in[9];
    const float* b2     = (const float*)d_in[10];
    const float* w1n    = (const float*)d_in[11];
    const float* b1n    = (const float*)d_in[12];
    const float* w2n    = (const float*)d_in[13];
    const float* b2n    = (const float*)d_in[14];

    const int N  = in_sizes[1];        // 1,000,000 nodes
    const int M  = in_sizes[4];        // 1024 dist-embedding rows
    const int Bn = out_size / 7;       // 4096 segments

    float* means    = (float*)d_ws;                    // 7 floats @ 0
    float* partials = (float*)d_ws + 256;              // Bn*PSTRIDE floats (2.16 MB), 1 KB-aligned
    float* out_vec  = (float*)d_out;                   // [B,6]
    float* out_norm = (float*)d_out + (size_t)Bn * 6;  // [B,1]

    const int nPartF4   = Bn * PSTRIDE / 4;            // float4 count to zero
    const int zeroBlks  = (nPartF4 + 255) / 256;
    const int nBlocks   = 2048;                        // 8192 waves
    const int nWaves    = nBlocks * 4;
    const int rpw       = (((N + nWaves - 1) / nWaves) + 3) & ~3;   // rows per wave, mult of 4

    prep_kernel<<<1 + zeroBlks, 256, 0, stream>>>(de, den, M, means, partials, nPartF4);
    stream_kernel<<<nBlocks, 256, 0, stream>>>(x, mask, seg, N, rpw, gate_w, gate_b, partials);
    combine_mlp_kernel<<<Bn, 256, 0, stream>>>(partials, w1, b1, w2, b2,
                                               w1n, b1n, w2n, b2n, means,
                                               out_vec, out_norm);
}